// Round 1
// baseline (97.831 us; speedup 1.0000x reference)
//
#include <hip/hip_runtime.h>
#include <float.h>
#include <math.h>

#define Ln 2048
#define Bn 64
#define Cn 512
#define Qn 512
#define Vn 512
#define NO 1536  // C*KW

// workspace layout (in floats)
#define OFF_KERN 0                           // [3][B][C]  = 98304
#define OFF_D    98304                       // [3][B][L]  = 393216
#define OFF_ET   (98304 + 393216)            // [B][L]     = 131072
#define OFF_SCR  (98304 + 393216 + 131072)   // shared: gemm partials (393216) / v partials (1048576)

// ---------------- K1: kernel_flat partial GEMM  C[b,o] = sum_k q[b,k] W[o,k]
// grid (24 o-tiles, 4 k-splits), block 256. Tile 64(b) x 64(o), K-chunk 64.
__global__ __launch_bounds__(256) void k1_gemm(const float* __restrict__ q,
                                               const float* __restrict__ W,
                                               float* __restrict__ gpart) {
    __shared__ float qs[64][65];
    __shared__ float wsm[64][65];
    const int o0 = blockIdx.x * 64;
    const int k0 = blockIdx.y * 128;
    const int tid = threadIdx.x;
    const int ty = tid >> 4, tx = tid & 15;

    float acc[4][4];
#pragma unroll
    for (int i = 0; i < 4; ++i)
#pragma unroll
        for (int j = 0; j < 4; ++j) acc[i][j] = 0.f;

    for (int kc = 0; kc < 128; kc += 64) {
#pragma unroll
        for (int r = 0; r < 4; ++r) {
            int idx = tid + r * 256;        // 1024 float4 slots per matrix
            int row = idx >> 4;
            int c4 = (idx & 15) << 2;
            float4 vq = *(const float4*)&q[row * Qn + k0 + kc + c4];
            qs[row][c4 + 0] = vq.x; qs[row][c4 + 1] = vq.y;
            qs[row][c4 + 2] = vq.z; qs[row][c4 + 3] = vq.w;
            float4 vw = *(const float4*)&W[(o0 + row) * Qn + k0 + kc + c4];
            wsm[row][c4 + 0] = vw.x; wsm[row][c4 + 1] = vw.y;
            wsm[row][c4 + 2] = vw.z; wsm[row][c4 + 3] = vw.w;
        }
        __syncthreads();
#pragma unroll 8
        for (int kk = 0; kk < 64; ++kk) {
            float aa[4], bb[4];
#pragma unroll
            for (int i = 0; i < 4; ++i) aa[i] = qs[ty * 4 + i][kk];
#pragma unroll
            for (int j = 0; j < 4; ++j) bb[j] = wsm[tx * 4 + j][kk];
#pragma unroll
            for (int i = 0; i < 4; ++i)
#pragma unroll
                for (int j = 0; j < 4; ++j) acc[i][j] += aa[i] * bb[j];
        }
        __syncthreads();
    }
    // gpart[ks][b][o]
#pragma unroll
    for (int i = 0; i < 4; ++i) {
        float4 w4 = make_float4(acc[i][0], acc[i][1], acc[i][2], acc[i][3]);
        *(float4*)&gpart[(blockIdx.y * 64 + ty * 4 + i) * NO + o0 + tx * 4] = w4;
    }
}

// ---------------- K1b: reduce k-splits + bias, transpose to kern[w][b][c]
__global__ __launch_bounds__(256) void k1b_reduce(const float* __restrict__ gpart,
                                                  const float* __restrict__ bias,
                                                  float* __restrict__ kern) {
    int idx = blockIdx.x * 256 + threadIdx.x;  // [0, 3*64*512)
    if (idx >= 3 * Bn * Cn) return;
    int w = idx / (Bn * Cn);
    int rem = idx - w * (Bn * Cn);
    int b = rem >> 9;          // / 512
    int c = rem & 511;
    int o = c * 3 + w;
    float s = bias[o];
#pragma unroll
    for (int ks = 0; ks < 4; ++ks) s += gpart[(ks * Bn + b) * NO + o];
    kern[idx] = s;
}

// ---------------- K2: d_w[t,b] = k[t,b,:] . kern[w][b][:], one wave = (b, 4 t's)
__global__ __launch_bounds__(256) void k2_dots(const float* __restrict__ kin,
                                               const float* __restrict__ kern,
                                               float* __restrict__ dpl) {
    const int wid = (blockIdx.x << 2) + (threadIdx.x >> 6);
    const int lane = threadIdx.x & 63;
    const int b = wid & 63;
    const int t0 = (wid >> 6) << 2;
    const int c0 = lane * 4;
    const int c1 = 1024 + lane * 4;  // bytes: 256 floats offset

    float4 kwA[3], kwB[3];
#pragma unroll
    for (int w = 0; w < 3; ++w) {
        const float* p = kern + (w * Bn + b) * Cn;
        kwA[w] = *(const float4*)((const char*)p + c0 * 4);
        kwB[w] = *(const float4*)&p[256 + lane * 4];
    }
#pragma unroll
    for (int ti = 0; ti < 4; ++ti) {
        const int t = t0 + ti;
        const float* kr = kin + (size_t)(t * Bn + b) * Cn;
        float4 a = *(const float4*)&kr[lane * 4];
        float4 bb = *(const float4*)&kr[256 + lane * 4];
        float acc[3];
#pragma unroll
        for (int w = 0; w < 3; ++w) {
            acc[w] = a.x * kwA[w].x + a.y * kwA[w].y + a.z * kwA[w].z + a.w * kwA[w].w
                   + bb.x * kwB[w].x + bb.y * kwB[w].y + bb.z * kwB[w].z + bb.w * kwB[w].w;
        }
#pragma unroll
        for (int off = 32; off; off >>= 1) {
            acc[0] += __shfl_xor(acc[0], off);
            acc[1] += __shfl_xor(acc[1], off);
            acc[2] += __shfl_xor(acc[2], off);
        }
        if (lane == 0) {
            dpl[(0 * Bn + b) * Ln + t] = acc[0];
            dpl[(1 * Bn + b) * Ln + t] = acc[1];
            dpl[(2 * Bn + b) * Ln + t] = acc[2];
        }
    }
}

// ---------------- K3: combine taps + masked softmax over t (one block per b)
__global__ __launch_bounds__(256) void k3_softmax(const float* __restrict__ dpl,
                                                  const int* __restrict__ kmask,
                                                  float* __restrict__ out_a,
                                                  float* __restrict__ out_e,
                                                  float* __restrict__ eT) {
    const int b = blockIdx.x;
    const int tid = threadIdx.x;
    const float* d0 = dpl + (0 * Bn + b) * Ln;
    const float* d1 = dpl + (1 * Bn + b) * Ln;
    const float* d2 = dpl + (2 * Bn + b) * Ln;

    float a[8];
    int m[8];
    float lmax = -FLT_MAX;
#pragma unroll
    for (int i = 0; i < 8; ++i) {
        int t = tid + i * 256;
        float val = d1[t];
        if (t > 0) val += d0[t - 1];
        if (t < Ln - 1) val += d2[t + 1];
        a[i] = val;
        m[i] = kmask[t * Bn + b];
        out_a[t * Bn + b] = val;
        if (m[i]) lmax = fmaxf(lmax, val);
    }
    __shared__ float smax[4];
    __shared__ float ssum[4];
#pragma unroll
    for (int off = 32; off; off >>= 1) lmax = fmaxf(lmax, __shfl_xor(lmax, off));
    if ((tid & 63) == 0) smax[tid >> 6] = lmax;
    __syncthreads();
    const float mx = fmaxf(fmaxf(smax[0], smax[1]), fmaxf(smax[2], smax[3]));

    float p[8];
    float lsum = 0.f;
#pragma unroll
    for (int i = 0; i < 8; ++i) {
        p[i] = m[i] ? expf(a[i] - mx) : 0.f;
        lsum += p[i];
    }
#pragma unroll
    for (int off = 32; off; off >>= 1) lsum += __shfl_xor(lsum, off);
    if ((tid & 63) == 0) ssum[tid >> 6] = lsum;
    __syncthreads();
    const float inv = 1.f / (ssum[0] + ssum[1] + ssum[2] + ssum[3]);
#pragma unroll
    for (int i = 0; i < 8; ++i) {
        int t = tid + i * 256;
        float e = p[i] * inv;
        out_e[t * Bn + b] = e;
        eT[b * Ln + t] = e;
    }
}

// ---------------- K4: partial attend, skipping e==0 rows (grid = 32 t-chunks x 64 b)
__global__ __launch_bounds__(256) void k4_pv(const float* __restrict__ v,
                                             const float* __restrict__ eT,
                                             float* __restrict__ vpart) {
    const int tc = blockIdx.x >> 6;
    const int b = blockIdx.x & 63;
    const int tid = threadIdx.x;
    const int t0 = tc * 64;
    const float* ebase = eT + b * Ln;
    float2 acc = make_float2(0.f, 0.f);
    for (int ti = 0; ti < 64; ++ti) {
        const int t = t0 + ti;
        const float e = ebase[t];
        if (e != 0.f) {
            const float2 vv = *(const float2*)&v[(size_t)(t * Bn + b) * Vn + tid * 2];
            acc.x += e * vv.x;
            acc.y += e * vv.y;
        }
    }
    *(float2*)&vpart[(tc * Bn + b) * Vn + tid * 2] = acc;
}

// ---------------- K5: reduce v partials -> attend[b, v]
__global__ __launch_bounds__(256) void k5_reduce(const float* __restrict__ vpart,
                                                 float* __restrict__ out_att) {
    const int idx = blockIdx.x * 256 + threadIdx.x;  // [0, 32768)
    float s = 0.f;
#pragma unroll
    for (int tc = 0; tc < 32; ++tc) s += vpart[tc * (Bn * Vn) + idx];
    out_att[idx] = s;
}

extern "C" void kernel_launch(void* const* d_in, const int* in_sizes, int n_in,
                              void* d_out, int out_size, void* d_ws, size_t ws_size,
                              hipStream_t stream) {
    const float* q = (const float*)d_in[0];
    const float* k = (const float*)d_in[1];
    const float* v = (const float*)d_in[2];
    const int* kmask = (const int*)d_in[3];
    const float* W = (const float*)d_in[4];
    const float* bias = (const float*)d_in[5];

    float* out = (float*)d_out;
    float* out_a = out;                      // [L, B]
    float* out_e = out + Ln * Bn;            // [L, B]
    float* out_att = out + 2 * Ln * Bn;      // [B, V]

    float* ws = (float*)d_ws;
    float* kern = ws + OFF_KERN;
    float* dpl = ws + OFF_D;
    float* eT = ws + OFF_ET;
    float* scr = ws + OFF_SCR;   // gemm partials then v partials (disjoint phases)

    k1_gemm<<<dim3(24, 4), 256, 0, stream>>>(q, W, scr);
    k1b_reduce<<<(3 * Bn * Cn + 255) / 256, 256, 0, stream>>>(scr, bias, kern);
    k2_dots<<<(Ln / 4 * Bn) / 4, 256, 0, stream>>>(k, kern, dpl);
    k3_softmax<<<Bn, 256, 0, stream>>>(dpl, kmask, out_a, out_e, eT);
    k4_pv<<<32 * Bn, 256, 0, stream>>>(v, eT, scr);
    k5_reduce<<<(Bn * Vn) / 256, 256, 0, stream>>>(scr, out_att);
}

// Round 2
// 95.222 us; speedup vs baseline: 1.0274x; 1.0274x over previous
//
#include <hip/hip_runtime.h>
#include <float.h>
#include <math.h>

#define Ln 2048
#define Bn 64
#define Cn 512
#define Qn 512
#define Vn 512
#define NO 1536   // C*KW

#define DROW 2064   // padded dpl row: 8 front pad + 2048 + 8 tail pad
#define DPAD 8

// workspace layout (in floats)
#define OFF_KERN 0                             // [3][B][C]        = 98304
#define OFF_DPL  98304                         // [3][B][DROW]     = 396288
#define OFF_STAT (98304 + 396288)              // [B][2]           = 128
#define OFF_SCR  (98304 + 396288 + 128)        // gemm partials (393216) / v partials (262144)

typedef float f4 __attribute__((ext_vector_type(4)));
typedef float f2 __attribute__((ext_vector_type(2)));

// ---------------- K1: kernel_flat partial GEMM  gpart[ks][b][o] = sum_k q[b,k] W[o,k]
__global__ __launch_bounds__(256) void k1_gemm(const float* __restrict__ q,
                                               const float* __restrict__ W,
                                               float* __restrict__ gpart) {
    __shared__ float qs[64][65];
    __shared__ float wsm[64][65];
    const int o0 = blockIdx.x * 64;
    const int k0 = blockIdx.y * 128;
    const int tid = threadIdx.x;
    const int ty = tid >> 4, tx = tid & 15;

    float acc[4][4];
#pragma unroll
    for (int i = 0; i < 4; ++i)
#pragma unroll
        for (int j = 0; j < 4; ++j) acc[i][j] = 0.f;

    for (int kc = 0; kc < 128; kc += 64) {
#pragma unroll
        for (int r = 0; r < 4; ++r) {
            int idx = tid + r * 256;
            int row = idx >> 4;
            int c4 = (idx & 15) << 2;
            float4 vq = *(const float4*)&q[row * Qn + k0 + kc + c4];
            qs[row][c4 + 0] = vq.x; qs[row][c4 + 1] = vq.y;
            qs[row][c4 + 2] = vq.z; qs[row][c4 + 3] = vq.w;
            float4 vw = *(const float4*)&W[(o0 + row) * Qn + k0 + kc + c4];
            wsm[row][c4 + 0] = vw.x; wsm[row][c4 + 1] = vw.y;
            wsm[row][c4 + 2] = vw.z; wsm[row][c4 + 3] = vw.w;
        }
        __syncthreads();
#pragma unroll 8
        for (int kk = 0; kk < 64; ++kk) {
            float aa[4], bb[4];
#pragma unroll
            for (int i = 0; i < 4; ++i) aa[i] = qs[ty * 4 + i][kk];
#pragma unroll
            for (int j = 0; j < 4; ++j) bb[j] = wsm[tx * 4 + j][kk];
#pragma unroll
            for (int i = 0; i < 4; ++i)
#pragma unroll
                for (int j = 0; j < 4; ++j) acc[i][j] += aa[i] * bb[j];
        }
        __syncthreads();
    }
#pragma unroll
    for (int i = 0; i < 4; ++i) {
        float4 w4 = make_float4(acc[i][0], acc[i][1], acc[i][2], acc[i][3]);
        *(float4*)&gpart[(blockIdx.y * 64 + ty * 4 + i) * NO + o0 + tx * 4] = w4;
    }
}

// ---------------- K1b: reduce k-splits + bias, transpose to kern[w][b][c]
__global__ __launch_bounds__(256) void k1b_reduce(const float* __restrict__ gpart,
                                                  const float* __restrict__ bias,
                                                  float* __restrict__ kern) {
    int idx = blockIdx.x * 256 + threadIdx.x;
    if (idx >= 3 * Bn * Cn) return;
    int w = idx / (Bn * Cn);
    int rem = idx - w * (Bn * Cn);
    int b = rem >> 9;
    int c = rem & 511;
    int o = c * 3 + w;
    float s = bias[o];
#pragma unroll
    for (int ks = 0; ks < 4; ++ks) s += gpart[(ks * Bn + b) * NO + o];
    kern[idx] = s;
}

// ---------------- K2: dplP[w][b][8+t] = k[t,b,:] . kern[w][b][:]; wave = (b, 8 t's)
__global__ __launch_bounds__(256) void k2_dots(const float* __restrict__ kin,
                                               const float* __restrict__ kern,
                                               float* __restrict__ dplP) {
    const int wid = (blockIdx.x << 2) + (threadIdx.x >> 6);
    const int lane = threadIdx.x & 63;
    const int b = wid & 63;
    const int t0 = (wid >> 6) << 3;

    f4 kwA[3], kwB[3];
#pragma unroll
    for (int w = 0; w < 3; ++w) {
        const f4* p = (const f4*)(kern + (w * Bn + b) * Cn);
        kwA[w] = p[lane];
        kwB[w] = p[64 + lane];
    }
#pragma unroll
    for (int ti = 0; ti < 8; ++ti) {
        const int t = t0 + ti;
        const f4* kr = (const f4*)(kin + ((size_t)t * Bn + b) * Cn);
        f4 a = __builtin_nontemporal_load(kr + lane);
        f4 c = __builtin_nontemporal_load(kr + 64 + lane);
        float acc0 = a.x * kwA[0].x + a.y * kwA[0].y + a.z * kwA[0].z + a.w * kwA[0].w
                   + c.x * kwB[0].x + c.y * kwB[0].y + c.z * kwB[0].z + c.w * kwB[0].w;
        float acc1 = a.x * kwA[1].x + a.y * kwA[1].y + a.z * kwA[1].z + a.w * kwA[1].w
                   + c.x * kwB[1].x + c.y * kwB[1].y + c.z * kwB[1].z + c.w * kwB[1].w;
        float acc2 = a.x * kwA[2].x + a.y * kwA[2].y + a.z * kwA[2].z + a.w * kwA[2].w
                   + c.x * kwB[2].x + c.y * kwB[2].y + c.z * kwB[2].z + c.w * kwB[2].w;
#pragma unroll
        for (int off = 32; off; off >>= 1) {
            acc0 += __shfl_xor(acc0, off);
            acc1 += __shfl_xor(acc1, off);
            acc2 += __shfl_xor(acc2, off);
        }
        if (lane == 0) {
            dplP[(0 * Bn + b) * DROW + DPAD + t] = acc0;
            dplP[(1 * Bn + b) * DROW + DPAD + t] = acc1;
            dplP[(2 * Bn + b) * DROW + DPAD + t] = acc2;
        }
    }
}

// ---------------- K3a: per-b masked softmax stats (mx, 1/sum)
__global__ __launch_bounds__(256) void k3a_stats(const float* __restrict__ dplP,
                                                 const int* __restrict__ kmask,
                                                 float* __restrict__ stats) {
    const int b = blockIdx.x;
    const int tid = threadIdx.x;
    const float* d0 = dplP + (0 * Bn + b) * DROW + DPAD;
    const float* d1 = dplP + (1 * Bn + b) * DROW + DPAD;
    const float* d2 = dplP + (2 * Bn + b) * DROW + DPAD;

    float av[8];
    int m[8];
    float lmax = -FLT_MAX;
#pragma unroll
    for (int i = 0; i < 8; ++i) {
        int t = tid + i * 256;
        float x0 = d0[t - 1];
        float x2 = d2[t + 1];
        float val = d1[t] + (t > 0 ? x0 : 0.f) + (t < Ln - 1 ? x2 : 0.f);
        av[i] = val;
        m[i] = kmask[t * Bn + b];
        if (m[i]) lmax = fmaxf(lmax, val);
    }
    __shared__ float red[4];
#pragma unroll
    for (int off = 32; off; off >>= 1) lmax = fmaxf(lmax, __shfl_xor(lmax, off));
    if ((tid & 63) == 0) red[tid >> 6] = lmax;
    __syncthreads();
    const float mx = fmaxf(fmaxf(red[0], red[1]), fmaxf(red[2], red[3]));
    __syncthreads();
    float lsum = 0.f;
#pragma unroll
    for (int i = 0; i < 8; ++i) lsum += m[i] ? __expf(av[i] - mx) : 0.f;
#pragma unroll
    for (int off = 32; off; off >>= 1) lsum += __shfl_xor(lsum, off);
    if ((tid & 63) == 0) red[tid >> 6] = lsum;
    __syncthreads();
    if (tid == 0) {
        float s = red[0] + red[1] + red[2] + red[3];
        stats[2 * b] = mx;
        stats[2 * b + 1] = 1.f / s;
    }
}

// ---------------- K34: emit a/e + sparse PV partials. block = (t-chunk of 256) x b
__global__ __launch_bounds__(256) void k34_emit_pv(const float* __restrict__ dplP,
                                                   const int* __restrict__ kmask,
                                                   const float* __restrict__ stats,
                                                   const float* __restrict__ v,
                                                   float* __restrict__ out_a,
                                                   float* __restrict__ out_e,
                                                   float* __restrict__ vpart) {
    const int c = blockIdx.x >> 6;    // 0..7
    const int b = blockIdx.x & 63;
    const int tid = threadIdx.x;
    const int t = c * 256 + tid;

    const float mx = stats[2 * b];
    const float inv = stats[2 * b + 1];
    const float x0 = dplP[(0 * Bn + b) * DROW + DPAD + t - 1];
    const float x1 = dplP[(1 * Bn + b) * DROW + DPAD + t];
    const float x2 = dplP[(2 * Bn + b) * DROW + DPAD + t + 1];
    const float a = x1 + (t > 0 ? x0 : 0.f) + (t < Ln - 1 ? x2 : 0.f);
    const int m = kmask[t * Bn + b];
    const float e = m ? __expf(a - mx) * inv : 0.f;
    out_a[t * Bn + b] = a;
    out_e[t * Bn + b] = e;

    __shared__ float es[256];
    __shared__ unsigned long long bm[4];
    es[tid] = e;
    unsigned long long bal = __ballot(e != 0.f);
    if ((tid & 63) == 0) bm[tid >> 6] = bal;
    __syncthreads();

    f2 acc;
    acc.x = 0.f;
    acc.y = 0.f;
#pragma unroll
    for (int w = 0; w < 4; ++w) {
        unsigned long long mm = bm[w];
        while (mm) {
            int bit = __ffsll((unsigned long long)mm) - 1;
            mm &= mm - 1;
            int tt = w * 64 + bit;
            float ee = es[tt];
            const f2* vrow = (const f2*)(v + (((size_t)(c * 256 + tt) * Bn + b) << 9));
            f2 vv = __builtin_nontemporal_load(vrow + tid);
            acc.x += ee * vv.x;
            acc.y += ee * vv.y;
        }
    }
    *(f2*)&vpart[((c * Bn + b) << 9) + tid * 2] = acc;
}

// ---------------- K5: reduce v partials -> attend[b, v]
__global__ __launch_bounds__(256) void k5_reduce(const float* __restrict__ vpart,
                                                 float* __restrict__ out_att) {
    const int idx = blockIdx.x * 256 + threadIdx.x;  // [0, 32768)
    float s = 0.f;
#pragma unroll
    for (int c = 0; c < 8; ++c) s += vpart[c * (Bn * Vn) + idx];
    out_att[idx] = s;
}

extern "C" void kernel_launch(void* const* d_in, const int* in_sizes, int n_in,
                              void* d_out, int out_size, void* d_ws, size_t ws_size,
                              hipStream_t stream) {
    const float* q = (const float*)d_in[0];
    const float* k = (const float*)d_in[1];
    const float* v = (const float*)d_in[2];
    const int* kmask = (const int*)d_in[3];
    const float* W = (const float*)d_in[4];
    const float* bias = (const float*)d_in[5];

    float* out = (float*)d_out;
    float* out_a = out;                      // [L, B]
    float* out_e = out + Ln * Bn;            // [L, B]
    float* out_att = out + 2 * Ln * Bn;      // [B, V]

    float* ws = (float*)d_ws;
    float* kern = ws + OFF_KERN;
    float* dplP = ws + OFF_DPL;
    float* stats = ws + OFF_STAT;
    float* scr = ws + OFF_SCR;   // gemm partials, later v partials (disjoint phases)

    k1_gemm<<<dim3(24, 4), 256, 0, stream>>>(q, W, scr);
    k1b_reduce<<<(3 * Bn * Cn + 255) / 256, 256, 0, stream>>>(scr, bias, kern);
    k2_dots<<<4096, 256, 0, stream>>>(k, kern, dplP);
    k3a_stats<<<Bn, 256, 0, stream>>>(dplP, kmask, stats);
    k34_emit_pv<<<8 * Bn, 256, 0, stream>>>(dplP, kmask, stats, v, out_a, out_e, scr);
    k5_reduce<<<(Bn * Vn) / 256, 256, 0, stream>>>(scr, out_att);
}